// Round 8
// baseline (355.501 us; speedup 1.0000x reference)
//
#include <hip/hip_runtime.h>
#include <hip/hip_bf16.h>

#define Bb   8
#define NPIX 16384
#define N0T  16384
#define N1T  4096
#define C0d  256
#define C1d  512

#define NKEY_P 131072
#define NKEY_0 131072
#define NKEY_1 32768
#define NKEYS  294912
#define SCAN_BLOCKS 288

#define NZINT (NKEYS * 2 + 512)
#define NZI4  ((NZINT + 3) / 4)          // 147,456 int4 slots

typedef __attribute__((ext_vector_type(8))) short bf16x8;
typedef __attribute__((ext_vector_type(4))) float f32x4;

// ---------- helpers ----------
__device__ __forceinline__ int pix_idx(float lx, float ly, int HW) {
  lx = fminf(fmaxf(lx, -1.f), 1.f);
  ly = fminf(fmaxf(ly, -1.f), 1.f);
  float half = (float)HW * 0.5f;
  int px = (int)rintf((lx + 1.0f) * half - 0.5f);
  int py = (int)rintf((ly + 1.0f) * half - 0.5f);
  px = min(max(px, 0), HW - 1);
  py = min(max(py, 0), HW - 1);
  return py * HW + px;
}

__device__ __forceinline__ short f2bf(float f) {
  union { __hip_bfloat16 h; short s; } u;
  u.h = __float2bfloat16(f);
  return u.s;
}
__device__ __forceinline__ float bf2f(short s) {
  return __uint_as_float(((unsigned)(unsigned short)s) << 16);
}

// ---------- merged prep: zero counters | cvt W01 | cvt conv_w | transpose dw ----------
// tid-partitioned: [0,NZI4) zero int4 | [NZI4, +32768) W01 | [+32768) conv_w | [+2304) dwT
#define PREP_T0 NZI4
#define PREP_T1 (PREP_T0 + 32768)
#define PREP_T2 (PREP_T1 + 32768)
#define PREP_T3 (PREP_T2 + 2304)
__global__ __launch_bounds__(256) void k_prep(
    int4* __restrict__ zp, const float* __restrict__ W01, short* __restrict__ W01bf,
    const float* __restrict__ cw, short* __restrict__ cwbf,
    const float* __restrict__ dww, float* __restrict__ dwT) {
  int tid = blockIdx.x * 256 + threadIdx.x;
  if (tid < PREP_T0) {
    zp[tid] = int4{0, 0, 0, 0};
  } else if (tid < PREP_T1) {
    int i = tid - PREP_T0;
    float4 f = *reinterpret_cast<const float4*>(&W01[i * 4]);
    short4 o = { f2bf(f.x), f2bf(f.y), f2bf(f.z), f2bf(f.w) };
    *reinterpret_cast<short4*>(&W01bf[i * 4]) = o;
  } else if (tid < PREP_T2) {
    int i = tid - PREP_T1;
    float4 f = *reinterpret_cast<const float4*>(&cw[i * 4]);
    short4 o = { f2bf(f.x), f2bf(f.y), f2bf(f.z), f2bf(f.w) };
    *reinterpret_cast<short4*>(&cwbf[i * 4]) = o;
  } else if (tid < PREP_T3) {
    int i = tid - PREP_T2;        // k*256 + c
    int k = i >> 8, c = i & 255;
    dwT[k * 256 + c] = dww[c * 9 + k];
  }
}

// ---------- CSR build ----------
__global__ __launch_bounds__(256) void k_count(
    const int* __restrict__ idx0, const int* __restrict__ idx1,
    const float* __restrict__ loc, int* __restrict__ counts) {
  int e = blockIdx.x * 256 + threadIdx.x;
  int b = e >> 14;
  float lx = loc[2 * e + 0], ly = loc[2 * e + 1];
  int kp = b * 16384 + pix_idx(lx, ly, 128);
  int k0 = NKEY_P + b * 16384 + idx0[e];
  int k1 = NKEY_P + NKEY_0 + b * 4096 + idx1[e];
  atomicAdd(&counts[kp], 1);
  atomicAdd(&counts[k0], 1);
  atomicAdd(&counts[k1], 1);
}

__global__ __launch_bounds__(256) void k_scan_block(int* __restrict__ cnt, int* __restrict__ bsum) {
  __shared__ int s[256];
  const int tid = threadIdx.x;
  const int base = blockIdx.x * 1024 + tid * 4;
  int4 v = *reinterpret_cast<const int4*>(&cnt[base]);
  int t1 = v.x + v.y, t2 = t1 + v.z, t3 = t2 + v.w;
  s[tid] = t3;
  __syncthreads();
  for (int d = 1; d < 256; d <<= 1) {
    int add = (tid >= d) ? s[tid - d] : 0;
    __syncthreads();
    s[tid] += add;
    __syncthreads();
  }
  int excl = tid ? s[tid - 1] : 0;
  int4 o;
  o.x = excl; o.y = excl + v.x; o.z = excl + t1; o.w = excl + t2;
  *reinterpret_cast<int4*>(&cnt[base]) = o;
  if (tid == 255) bsum[blockIdx.x] = s[255];
}

__global__ __launch_bounds__(512) void k_scan_top(int* __restrict__ bsum) {
  __shared__ int s[512];
  const int tid = threadIdx.x;
  int v = (tid < SCAN_BLOCKS) ? bsum[tid] : 0;
  s[tid] = v;
  __syncthreads();
  for (int d = 1; d < 512; d <<= 1) {
    int add = (tid >= d) ? s[tid - d] : 0;
    __syncthreads();
    s[tid] += add;
    __syncthreads();
  }
  int excl = tid ? s[tid - 1] : 0;
  if (tid < SCAN_BLOCKS) bsum[tid] = excl;
}

__global__ __launch_bounds__(256) void k_scan_add(int* __restrict__ off, const int* __restrict__ bsum) {
  int add = bsum[blockIdx.x];
  const int base = blockIdx.x * 1024 + threadIdx.x * 4;
  int4 v = *reinterpret_cast<const int4*>(&off[base]);
  v.x += add; v.y += add; v.z += add; v.w += add;
  *reinterpret_cast<int4*>(&off[base]) = v;
}

__global__ __launch_bounds__(256) void k_fill(
    const int* __restrict__ idx0, const int* __restrict__ idx1,
    const float* __restrict__ w0, const float* __restrict__ w1,
    const float* __restrict__ loc, const int* __restrict__ offs,
    int* __restrict__ cursor, int* __restrict__ intA,
    int* __restrict__ intB, float* __restrict__ fW) {
  int e = blockIdx.x * 256 + threadIdx.x;
  int b = e >> 14;
  float lx = loc[2 * e + 0], ly = loc[2 * e + 1];
  int i0 = idx0[e], i1 = idx1[e];
  int kp = b * 16384 + pix_idx(lx, ly, 128);
  int k0 = NKEY_P + b * 16384 + i0;
  int k1 = NKEY_P + NKEY_0 + b * 4096 + i1;
  int pP = offs[kp] + atomicAdd(&cursor[kp], 1);
  intA[pP] = b * 16384 + i0;
  int p0 = offs[k0] + atomicAdd(&cursor[k0], 1);
  intA[p0] = b * 4096 + i1;
  fW[p0 - NKEY_P] = w0[e];
  int p1 = offs[k1] + atomicAdd(&cursor[k1], 1);
  intA[p1] = b * 4096 + pix_idx(lx, ly, 64);
  intB[p1 - (NKEY_P + NKEY_0)] = b * 16384 + i0;
  fW[p1 - NKEY_P] = w1[e];
}

// ---------- phase 1: token2map mean -> dense bf16 map [131072 pixel-rows][256] ----------
__global__ __launch_bounds__(256) void k_t2m_mean(
    const float* __restrict__ x0, const int* __restrict__ offs,
    const int* __restrict__ lens, const int* __restrict__ intA,
    short* __restrict__ map) {
  int key = blockIdx.x * 4 + (threadIdx.x >> 6);   // pixel-row key [0, 131072)
  int lane = threadIdx.x & 63;
  int c4 = lane * 4;
  int st = offs[key];
  int ln = lens[key];
  float sx = 0.f, sy = 0.f, sz = 0.f, sw = 0.f;
  for (int i = 0; i < ln; ++i) {
    int row = intA[st + i];
    float4 v = *reinterpret_cast<const float4*>(&x0[(size_t)row * C0d + c4]);
    sx += v.x; sy += v.y; sz += v.z; sw += v.w;
  }
  float inv = 1.f / ((float)ln + 1e-6f);
  short4 o = { f2bf(sx * inv), f2bf(sy * inv), f2bf(sz * inv), f2bf(sw * inv) };
  *reinterpret_cast<short4*>(&map[(size_t)key * C0d + c4]) = o;
}

// ---------- phase 2: dense depthwise 3x3 s2 on bf16 map -> xm2 bf16 ----------
__global__ __launch_bounds__(256) void k_conv_dense(
    const short* __restrict__ map, const float* __restrict__ dwT,
    short* __restrict__ xm2) {
  int byx = blockIdx.x * 4 + (threadIdx.x >> 6);
  int lane = threadIdx.x & 63;
  int c4 = lane * 4;
  int b = byx >> 12;
  int yx = byx & 4095;
  int y = yx >> 6, x = yx & 63;
  float ax = 0.f, ay = 0.f, az = 0.f, aw = 0.f;
#pragma unroll
  for (int ky = 0; ky < 3; ++ky) {
    int iy = 2 * y - 1 + ky;
    if ((unsigned)iy >= 128u) continue;
#pragma unroll
    for (int kx = 0; kx < 3; ++kx) {
      int ix = 2 * x - 1 + kx;
      if ((unsigned)ix >= 128u) continue;
      size_t p = ((size_t)(b * 16384 + iy * 128 + ix)) * C0d + c4;
      short4 m = *reinterpret_cast<const short4*>(&map[p]);
      float4 w = *reinterpret_cast<const float4*>(&dwT[(ky * 3 + kx) * 256 + c4]);
      ax += bf2f(m.x) * w.x; ay += bf2f(m.y) * w.y;
      az += bf2f(m.z) * w.z; aw += bf2f(m.w) * w.w;
    }
  }
  short4 o = { f2bf(ax), f2bf(ay), f2bf(az), f2bf(aw) };
  *reinterpret_cast<short4*>(&xm2[(size_t)byx * C0d + c4]) = o;
}

// ---------- bf16 MFMA GEMM, BM=128 BN=128, 256 thr (4 waves 2x2, wave 64x64) ----------
template <int KDIM, bool FUSE, bool ABF16, bool OBF16>
__global__ __launch_bounds__(256) void k_gemm_t128(
    const void* __restrict__ Av, const short* __restrict__ Bbf,
    const float* __restrict__ g, const float* __restrict__ beta,
    const float* __restrict__ mean, const float* __restrict__ var,
    const float* __restrict__ resid, void* __restrict__ Cv, int N) {
  __shared__ __align__(16) short Als[4][128][8];
  __shared__ __align__(16) short Bls[4][128][8];
  const int t = threadIdx.x;
  const int lane = t & 63;
  const int wave = t >> 6;
  const int wm = wave >> 1;
  const int wn = wave & 1;
  const int m0 = blockIdx.x * 128;
  const int n0 = blockIdx.y * 128;
  const int l15 = lane & 15;
  const int kb = lane >> 4;
  const int srow = t >> 1;
  const int shalf = t & 1;
  f32x4 acc[4][4] = {};

  for (int kt = 0; kt < KDIM; kt += 32) {
    if constexpr (ABF16) {
      const short* A = (const short*)Av;
      size_t base = (size_t)(m0 + srow) * KDIM + kt + shalf * 16;
      bf16x8 v0 = *reinterpret_cast<const bf16x8*>(&A[base]);
      bf16x8 v1 = *reinterpret_cast<const bf16x8*>(&A[base + 8]);
      *reinterpret_cast<bf16x8*>(&Als[shalf * 2 + 0][srow][0]) = v0;
      *reinterpret_cast<bf16x8*>(&Als[shalf * 2 + 1][srow][0]) = v1;
    } else {
      const float* A = (const float*)Av;
      size_t base = (size_t)(m0 + srow) * KDIM + kt + shalf * 16;
      float4 f0 = *reinterpret_cast<const float4*>(&A[base + 0]);
      float4 f1 = *reinterpret_cast<const float4*>(&A[base + 4]);
      float4 f2 = *reinterpret_cast<const float4*>(&A[base + 8]);
      float4 f3 = *reinterpret_cast<const float4*>(&A[base + 12]);
      bf16x8 v0 = { f2bf(f0.x), f2bf(f0.y), f2bf(f0.z), f2bf(f0.w),
                    f2bf(f1.x), f2bf(f1.y), f2bf(f1.z), f2bf(f1.w) };
      bf16x8 v1 = { f2bf(f2.x), f2bf(f2.y), f2bf(f2.z), f2bf(f2.w),
                    f2bf(f3.x), f2bf(f3.y), f2bf(f3.z), f2bf(f3.w) };
      *reinterpret_cast<bf16x8*>(&Als[shalf * 2 + 0][srow][0]) = v0;
      *reinterpret_cast<bf16x8*>(&Als[shalf * 2 + 1][srow][0]) = v1;
    }
    {
      size_t base = (size_t)(n0 + srow) * KDIM + kt + shalf * 16;
      bf16x8 v0 = *reinterpret_cast<const bf16x8*>(&Bbf[base]);
      bf16x8 v1 = *reinterpret_cast<const bf16x8*>(&Bbf[base + 8]);
      *reinterpret_cast<bf16x8*>(&Bls[shalf * 2 + 0][srow][0]) = v0;
      *reinterpret_cast<bf16x8*>(&Bls[shalf * 2 + 1][srow][0]) = v1;
    }
    __syncthreads();
    bf16x8 af[4], bfr[4];
#pragma unroll
    for (int r = 0; r < 4; ++r)
      af[r] = *reinterpret_cast<const bf16x8*>(&Als[kb][wm * 64 + r * 16 + l15][0]);
#pragma unroll
    for (int s = 0; s < 4; ++s)
      bfr[s] = *reinterpret_cast<const bf16x8*>(&Bls[kb][wn * 64 + s * 16 + l15][0]);
#pragma unroll
    for (int r = 0; r < 4; ++r)
#pragma unroll
      for (int s = 0; s < 4; ++s)
        acc[r][s] = __builtin_amdgcn_mfma_f32_16x16x32_bf16(af[r], bfr[s], acc[r][s], 0, 0, 0);
    __syncthreads();
  }

  const int r0 = (lane >> 4) * 4;
#pragma unroll
  for (int s = 0; s < 4; ++s) {
    int col = n0 + wn * 64 + s * 16 + l15;
    float sc = g[col] * rsqrtf(var[col] + 1e-5f);
    float sh = beta[col] - mean[col] * sc;
#pragma unroll
    for (int r = 0; r < 4; ++r) {
      int rowb = m0 + wm * 64 + r * 16 + r0;
#pragma unroll
      for (int j = 0; j < 4; ++j) {
        int row = rowb + j;
        float v = acc[r][s][j] * sc + sh;
        if (FUSE) {
          v += resid[(size_t)row * N + col];
          v = fmaxf(v, 0.f);
        }
        if (OBF16) ((short*)Cv)[(size_t)row * N + col] = f2bf(v);
        else       ((float*)Cv)[(size_t)row * N + col] = v;
      }
    }
  }
}

// ---------- out0 = relu(x0 + gather(srcb_bf16,w)/(den+eps)) ----------
__global__ __launch_bounds__(256) void k_out0_v4(
    const short* __restrict__ srcb, const float* __restrict__ x0,
    const int* __restrict__ offs, const int* __restrict__ lens,
    const int* __restrict__ intA, const float* __restrict__ fW,
    float* __restrict__ out0) {
  int row = blockIdx.x * 4 + (threadIdx.x >> 6);
  int lane = threadIdx.x & 63;
  int c4 = lane * 4;
  int key = NKEY_P + row;
  int st = offs[key];
  int ln = lens[key];
  float ax = 0.f, ay = 0.f, az = 0.f, aw = 0.f, den = 0.f;
  for (int i = 0; i < ln; ++i) {
    int sr = intA[st + i];
    float w = fW[st + i - NKEY_P];
    short4 v = *reinterpret_cast<const short4*>(&srcb[(size_t)sr * C0d + c4]);
    ax += bf2f(v.x) * w; ay += bf2f(v.y) * w;
    az += bf2f(v.z) * w; aw += bf2f(v.w) * w;
    den += w;
  }
  float inv = 1.f / (den + 1e-6f);
  size_t o = (size_t)row * C0d + c4;
  float4 xv = *reinterpret_cast<const float4*>(&x0[o]);
  float4 r;
  r.x = fmaxf(xv.x + ax * inv, 0.f);
  r.y = fmaxf(xv.y + ay * inv, 0.f);
  r.z = fmaxf(xv.z + az * inv, 0.f);
  r.w = fmaxf(xv.w + aw * inv, 0.f);
  *reinterpret_cast<float4*>(&out0[o]) = r;
}

// ---------- xdf(bf16) = bn1( gd/den * skip + gb/den ) ----------
__global__ __launch_bounds__(256) void k_out1_pre_v4(
    const short* __restrict__ xm2, const float* __restrict__ x0,
    const int* __restrict__ offs, const int* __restrict__ lens,
    const int* __restrict__ intA, const int* __restrict__ intB,
    const float* __restrict__ fW, const float* __restrict__ skip_w,
    const float* __restrict__ g, const float* __restrict__ beta,
    const float* __restrict__ mean, const float* __restrict__ var,
    short* __restrict__ xdf) {
  int row = blockIdx.x * 4 + (threadIdx.x >> 6);
  int lane = threadIdx.x & 63;
  int c4 = lane * 4;
  int key = NKEY_P + NKEY_0 + row;
  int st = offs[key];
  int ln = lens[key];
  float bx = 0.f, by = 0.f, bz = 0.f, bw = 0.f;
  float dx = 0.f, dy = 0.f, dz = 0.f, dw = 0.f, den = 0.f;
  for (int i = 0; i < ln; ++i) {
    int pr = intA[st + i];
    int sr = intB[st + i - (NKEY_P + NKEY_0)];
    float w = fW[st + i - NKEY_P];
    short4 vb = *reinterpret_cast<const short4*>(&xm2[(size_t)pr * C0d + c4]);
    float4 vd = *reinterpret_cast<const float4*>(&x0[(size_t)sr * C0d + c4]);
    bx += bf2f(vb.x) * w; by += bf2f(vb.y) * w;
    bz += bf2f(vb.z) * w; bw += bf2f(vb.w) * w;
    dx += vd.x * w; dy += vd.y * w; dz += vd.z * w; dw += vd.w * w;
    den += w;
  }
  float inv = 1.f / (den + 1e-6f);
  float4 sk = *reinterpret_cast<const float4*>(&skip_w[c4]);
  float4 gg = *reinterpret_cast<const float4*>(&g[c4]);
  float4 bb = *reinterpret_cast<const float4*>(&beta[c4]);
  float4 mm = *reinterpret_cast<const float4*>(&mean[c4]);
  float4 vv = *reinterpret_cast<const float4*>(&var[c4]);
  float s0 = gg.x * rsqrtf(vv.x + 1e-5f), h0 = bb.x - mm.x * s0;
  float s1 = gg.y * rsqrtf(vv.y + 1e-5f), h1 = bb.y - mm.y * s1;
  float s2 = gg.z * rsqrtf(vv.z + 1e-5f), h2 = bb.z - mm.z * s2;
  float s3 = gg.w * rsqrtf(vv.w + 1e-5f), h3 = bb.w - mm.w * s3;
  short4 o;
  o.x = f2bf((dx * inv * sk.x + bx * inv) * s0 + h0);
  o.y = f2bf((dy * inv * sk.y + by * inv) * s1 + h1);
  o.z = f2bf((dz * inv * sk.z + bz * inv) * s2 + h2);
  o.w = f2bf((dw * inv * sk.w + bw * inv) * s3 + h3);
  *reinterpret_cast<short4*>(&xdf[(size_t)row * C0d + c4]) = o;
}

extern "C" void kernel_launch(void* const* d_in, const int* in_sizes, int n_in,
                              void* d_out, int out_size, void* d_ws, size_t ws_size,
                              hipStream_t stream) {
  const float* x0   = (const float*)d_in[0];
  const float* x1   = (const float*)d_in[1];
  const int*   idx0 = (const int*)d_in[2];
  const int*   idx1 = (const int*)d_in[3];
  const float* w0   = (const float*)d_in[4];
  const float* w1   = (const float*)d_in[5];
  const float* loc  = (const float*)d_in[6];
  const float* W01  = (const float*)d_in[7];
  const float* bn01_g = (const float*)d_in[8];
  const float* bn01_b = (const float*)d_in[9];
  const float* bn01_m = (const float*)d_in[10];
  const float* bn01_v = (const float*)d_in[11];
  const float* dw_w   = (const float*)d_in[12];
  const float* skip_w = (const float*)d_in[13];
  const float* bn1_g  = (const float*)d_in[14];
  const float* bn1_b  = (const float*)d_in[15];
  const float* bn1_m  = (const float*)d_in[16];
  const float* bn1_v  = (const float*)d_in[17];
  const float* conv_w = (const float*)d_in[18];
  const float* bn2_g  = (const float*)d_in[19];
  const float* bn2_b  = (const float*)d_in[20];
  const float* bn2_m  = (const float*)d_in[21];
  const float* bn2_v  = (const float*)d_in[22];

  float* out = (float*)d_out;
  float* num0 = out;                       // out0 [131072 x 256]
  float* out1 = out + 33554432;            // out1 [32768 x 512]

  // ---- workspace layout ----
  int*   counts = (int*)d_ws;              // NKEYS (-> offsets)
  int*   cursor = counts + NKEYS;          // NKEYS (-> lengths)
  int*   bsum   = cursor + NKEYS;          // 512
  int*   intA   = bsum + 512;              // 393216
  int*   intB   = intA + 393216;           // 131072
  float* fW     = (float*)(intB + 131072); // 262144
  float* dwT    = fW + 262144;             // 2560 (2304 used)
  short* W01bf  = (short*)(dwT + 2560);    // 131072 bf16
  short* cwbf   = W01bf + 131072;          // 131072 bf16
  short* map    = cwbf + 131072;           // 33,554,432 bf16 (dense 128x128 mean map)
  short* xm2    = map + 33554432;          // 8,388,608 bf16
  short* srcb   = xm2 + 8388608;           // 8,388,608 bf16
  short* xdf    = srcb + 8388608;          // 8,388,608 bf16

  const int nbp = Bb * NPIX;               // 131072

  // merged prep: zero CSR counters + cvt W01/conv_w + transpose dw
  k_prep<<<(PREP_T3 + 255) / 256, 256, 0, stream>>>(
      (int4*)d_ws, W01, W01bf, conv_w, cwbf, dw_w, dwT);

  // CSR build
  k_count<<<nbp / 256, 256, 0, stream>>>(idx0, idx1, loc, counts);
  k_scan_block<<<SCAN_BLOCKS, 256, 0, stream>>>(counts, bsum);
  k_scan_top<<<1, 512, 0, stream>>>(bsum);
  k_scan_add<<<SCAN_BLOCKS, 256, 0, stream>>>(counts, bsum);
  k_fill<<<nbp / 256, 256, 0, stream>>>(idx0, idx1, w0, w1, loc, counts, cursor,
                                        intA, intB, fW);

  // phase 1: dense pixel mean map (bf16)
  k_t2m_mean<<<NKEY_P / 4, 256, 0, stream>>>(x0, counts, cursor, intA, map);

  // phase 2: dense depthwise conv -> xm2 (bf16)
  k_conv_dense<<<Bb * 4096 / 4, 256, 0, stream>>>(map, dwT, xm2);

  // srcb(bf16) = bn01(x1 @ W01^T)   [32768 x 256]
  {
    dim3 grid(32768 / 128, 256 / 128);
    k_gemm_t128<512, false, false, true><<<grid, 256, 0, stream>>>(
        (const void*)x1, W01bf, bn01_g, bn01_b, bn01_m, bn01_v, nullptr, (void*)srcb, 256);
  }

  // out0 = relu(x0 + gather(srcb))
  k_out0_v4<<<nbp / 4, 256, 0, stream>>>(srcb, x0, counts, cursor, intA, fW, num0);

  // xdf(bf16) = bn1(gather_d*skip + gather_b)
  k_out1_pre_v4<<<Bb * N1T / 4, 256, 0, stream>>>(xm2, x0, counts, cursor, intA, intB,
                                                  fW, skip_w, bn1_g, bn1_b, bn1_m, bn1_v,
                                                  xdf);

  // out1 = relu(x1 + bn2(xdf @ conv_w^T))  [32768 x 512]
  {
    dim3 grid(32768 / 128, 512 / 128);
    k_gemm_t128<256, true, true, false><<<grid, 256, 0, stream>>>(
        (const void*)xdf, cwbf, bn2_g, bn2_b, bn2_m, bn2_v, x1, (void*)out1, 512);
  }
}

// Round 10
// 269.144 us; speedup vs baseline: 1.3209x; 1.3209x over previous
//
#include <hip/hip_runtime.h>
#include <hip/hip_bf16.h>

#define Bb   8
#define NPIX 16384
#define N0T  16384
#define N1T  4096
#define C0d  256
#define C1d  512

#define NKEY_P 131072
#define NKEY_0 131072
#define NKEY_1 32768
#define NKEYS  294912
#define SCAN_BLOCKS 288

#define NZINT (NKEYS * 2 + 512)
#define NZI4  ((NZINT + 3) / 4)

typedef __attribute__((ext_vector_type(8))) short bf16x8;
typedef __attribute__((ext_vector_type(4))) float f32x4;

// ---------- helpers ----------
__device__ __forceinline__ int pix_idx(float lx, float ly, int HW) {
  lx = fminf(fmaxf(lx, -1.f), 1.f);
  ly = fminf(fmaxf(ly, -1.f), 1.f);
  float half = (float)HW * 0.5f;
  int px = (int)rintf((lx + 1.0f) * half - 0.5f);
  int py = (int)rintf((ly + 1.0f) * half - 0.5f);
  px = min(max(px, 0), HW - 1);
  py = min(max(py, 0), HW - 1);
  return py * HW + px;
}

__device__ __forceinline__ short f2bf(float f) {
  union { __hip_bfloat16 h; short s; } u;
  u.h = __float2bfloat16(f);
  return u.s;
}
__device__ __forceinline__ float bf2f(short s) {
  return __uint_as_float(((unsigned)(unsigned short)s) << 16);
}

// ---------- merged prep: zero counters | cvt W01 | cvt conv_w | transpose dw ----------
#define PREP_T0 NZI4
#define PREP_T1 (PREP_T0 + 32768)
#define PREP_T2 (PREP_T1 + 32768)
#define PREP_T3 (PREP_T2 + 2304)
__global__ __launch_bounds__(256) void k_prep(
    int4* __restrict__ zp, const float* __restrict__ W01, short* __restrict__ W01bf,
    const float* __restrict__ cw, short* __restrict__ cwbf,
    const float* __restrict__ dww, float* __restrict__ dwT) {
  int tid = blockIdx.x * 256 + threadIdx.x;
  if (tid < PREP_T0) {
    zp[tid] = int4{0, 0, 0, 0};
  } else if (tid < PREP_T1) {
    int i = tid - PREP_T0;
    float4 f = *reinterpret_cast<const float4*>(&W01[i * 4]);
    short4 o = { f2bf(f.x), f2bf(f.y), f2bf(f.z), f2bf(f.w) };
    *reinterpret_cast<short4*>(&W01bf[i * 4]) = o;
  } else if (tid < PREP_T2) {
    int i = tid - PREP_T1;
    float4 f = *reinterpret_cast<const float4*>(&cw[i * 4]);
    short4 o = { f2bf(f.x), f2bf(f.y), f2bf(f.z), f2bf(f.w) };
    *reinterpret_cast<short4*>(&cwbf[i * 4]) = o;
  } else if (tid < PREP_T3) {
    int i = tid - PREP_T2;
    int k = i >> 8, c = i & 255;
    dwT[k * 256 + c] = dww[c * 9 + k];
  }
}

// ---------- CSR build ----------
__global__ __launch_bounds__(256) void k_count(
    const int* __restrict__ idx0, const int* __restrict__ idx1,
    const float* __restrict__ loc, int* __restrict__ counts) {
  int e = blockIdx.x * 256 + threadIdx.x;
  int b = e >> 14;
  float lx = loc[2 * e + 0], ly = loc[2 * e + 1];
  int kp = b * 16384 + pix_idx(lx, ly, 128);
  int k0 = NKEY_P + b * 16384 + idx0[e];
  int k1 = NKEY_P + NKEY_0 + b * 4096 + idx1[e];
  atomicAdd(&counts[kp], 1);
  atomicAdd(&counts[k0], 1);
  atomicAdd(&counts[k1], 1);
}

// block-local exclusive scan; bsum[blk] = block total
__global__ __launch_bounds__(256) void k_scan_block(int* __restrict__ cnt, int* __restrict__ bsum) {
  __shared__ int s[256];
  const int tid = threadIdx.x;
  const int base = blockIdx.x * 1024 + tid * 4;
  int4 v = *reinterpret_cast<const int4*>(&cnt[base]);
  int t1 = v.x + v.y, t2 = t1 + v.z, t3 = t2 + v.w;
  s[tid] = t3;
  __syncthreads();
  for (int d = 1; d < 256; d <<= 1) {
    int add = (tid >= d) ? s[tid - d] : 0;
    __syncthreads();
    s[tid] += add;
    __syncthreads();
  }
  int excl = tid ? s[tid - 1] : 0;
  int4 o;
  o.x = excl; o.y = excl + v.x; o.z = excl + t1; o.w = excl + t2;
  *reinterpret_cast<int4*>(&cnt[base]) = o;
  if (tid == 255) bsum[blockIdx.x] = s[255];
}

// bsum -> global exclusive prefix of block totals
__global__ __launch_bounds__(512) void k_scan_top(int* __restrict__ bsum) {
  __shared__ int s[512];
  const int tid = threadIdx.x;
  int v = (tid < SCAN_BLOCKS) ? bsum[tid] : 0;
  s[tid] = v;
  __syncthreads();
  for (int d = 1; d < 512; d <<= 1) {
    int add = (tid >= d) ? s[tid - d] : 0;
    __syncthreads();
    s[tid] += add;
    __syncthreads();
  }
  int excl = tid ? s[tid - 1] : 0;
  if (tid < SCAN_BLOCKS) bsum[tid] = excl;
}

// global offset of a key = counts[key] (block-local prefix) + bsum[key>>10]
__device__ __forceinline__ int g_off(const int* __restrict__ cnt,
                                     const int* __restrict__ bsum, int key) {
  return cnt[key] + bsum[key >> 10];
}

__global__ __launch_bounds__(256) void k_fill(
    const int* __restrict__ idx0, const int* __restrict__ idx1,
    const float* __restrict__ w0, const float* __restrict__ w1,
    const float* __restrict__ loc, const int* __restrict__ offs,
    const int* __restrict__ bsum,
    int* __restrict__ cursor, int* __restrict__ intA,
    int* __restrict__ intB, float* __restrict__ fW) {
  int e = blockIdx.x * 256 + threadIdx.x;
  int b = e >> 14;
  float lx = loc[2 * e + 0], ly = loc[2 * e + 1];
  int i0 = idx0[e], i1 = idx1[e];
  int kp = b * 16384 + pix_idx(lx, ly, 128);
  int k0 = NKEY_P + b * 16384 + i0;
  int k1 = NKEY_P + NKEY_0 + b * 4096 + i1;
  int pP = g_off(offs, bsum, kp) + atomicAdd(&cursor[kp], 1);
  intA[pP] = b * 16384 + i0;
  int p0 = g_off(offs, bsum, k0) + atomicAdd(&cursor[k0], 1);
  intA[p0] = b * 4096 + i1;
  fW[p0 - NKEY_P] = w0[e];
  int p1 = g_off(offs, bsum, k1) + atomicAdd(&cursor[k1], 1);
  intA[p1] = b * 4096 + pix_idx(lx, ly, 64);
  intB[p1 - (NKEY_P + NKEY_0)] = b * 16384 + i0;
  fW[p1 - NKEY_P] = w1[e];
}

// ---------- fused token2map + normalize + dw 3x3 s2 -> xm2 bf16 (R4 winner) ----------
__global__ __launch_bounds__(256) void k_conv_v4(
    const float* __restrict__ x0, const int* __restrict__ offs,
    const int* __restrict__ bsum, const int* __restrict__ lens,
    const int* __restrict__ intA, const float* __restrict__ dwT,
    short* __restrict__ xm2) {
  int byx = blockIdx.x * 4 + (threadIdx.x >> 6);
  int lane = threadIdx.x & 63;
  int c4 = lane * 4;
  int b = byx >> 12;
  int yx = byx & 4095;
  int y = yx >> 6, x = yx & 63;
  float ax = 0.f, ay = 0.f, az = 0.f, aw = 0.f;
#pragma unroll
  for (int ky = 0; ky < 3; ++ky) {
    int iy = 2 * y - 1 + ky;
    if ((unsigned)iy >= 128u) continue;
#pragma unroll
    for (int kx = 0; kx < 3; ++kx) {
      int ix = 2 * x - 1 + kx;
      if ((unsigned)ix >= 128u) continue;
      int key = b * 16384 + iy * 128 + ix;
      int st = g_off(offs, bsum, key);
      int ln = lens[key];
      float sx = 0.f, sy = 0.f, sz = 0.f, sw = 0.f;
      for (int i = 0; i < ln; ++i) {
        int row = intA[st + i];
        float4 v = *reinterpret_cast<const float4*>(&x0[(size_t)row * C0d + c4]);
        sx += v.x; sy += v.y; sz += v.z; sw += v.w;
      }
      float inv = 1.f / ((float)ln + 1e-6f);
      float4 w = *reinterpret_cast<const float4*>(&dwT[(ky * 3 + kx) * 256 + c4]);
      ax += sx * inv * w.x; ay += sy * inv * w.y;
      az += sz * inv * w.z; aw += sw * inv * w.w;
    }
  }
  short4 o = { f2bf(ax), f2bf(ay), f2bf(az), f2bf(aw) };
  *reinterpret_cast<short4*>(&xm2[(size_t)byx * C0d + c4]) = o;
}

// ---------- bf16 MFMA GEMM (R4 tile: BM=128 BN=64 BK=32, 4 waves 2x2) ----------
// A: f32 (cvt in staging) or bf16; B: pre-converted bf16 [N][K].
template <int KDIM, bool FUSE, bool ABF16, bool OBF16>
__global__ __launch_bounds__(256) void k_gemm_mfma(
    const void* __restrict__ Av, const short* __restrict__ Bbf,
    const float* __restrict__ g, const float* __restrict__ beta,
    const float* __restrict__ mean, const float* __restrict__ var,
    const float* __restrict__ resid, void* __restrict__ Cv, int N) {
  __shared__ __align__(16) short Als[4][128][8];   // [k/8][m][k%8]
  __shared__ __align__(16) short Bls[4][64][8];
  const int t = threadIdx.x;
  const int lane = t & 63;
  const int wave = t >> 6;
  const int wm = wave >> 1;
  const int wn = wave & 1;
  const int m0 = blockIdx.x * 128;
  const int n0 = blockIdx.y * 64;
  const int l15 = lane & 15;
  const int kb = lane >> 4;
  const int arow = t >> 1, ahalf = t & 1;   // A: 16 k-elems/thread
  const int brow = t >> 2, bq = t & 3;      // B: 8 k-elems/thread (bf16)
  f32x4 acc[4][2] = {};

  for (int kt = 0; kt < KDIM; kt += 32) {
    if constexpr (ABF16) {
      const short* A = (const short*)Av;
      size_t base = (size_t)(m0 + arow) * KDIM + kt + ahalf * 16;
      bf16x8 v0 = *reinterpret_cast<const bf16x8*>(&A[base]);
      bf16x8 v1 = *reinterpret_cast<const bf16x8*>(&A[base + 8]);
      *reinterpret_cast<bf16x8*>(&Als[ahalf * 2 + 0][arow][0]) = v0;
      *reinterpret_cast<bf16x8*>(&Als[ahalf * 2 + 1][arow][0]) = v1;
    } else {
      const float* A = (const float*)Av;
      size_t base = (size_t)(m0 + arow) * KDIM + kt + ahalf * 16;
      float4 f0 = *reinterpret_cast<const float4*>(&A[base + 0]);
      float4 f1 = *reinterpret_cast<const float4*>(&A[base + 4]);
      float4 f2 = *reinterpret_cast<const float4*>(&A[base + 8]);
      float4 f3 = *reinterpret_cast<const float4*>(&A[base + 12]);
      bf16x8 v0 = { f2bf(f0.x), f2bf(f0.y), f2bf(f0.z), f2bf(f0.w),
                    f2bf(f1.x), f2bf(f1.y), f2bf(f1.z), f2bf(f1.w) };
      bf16x8 v1 = { f2bf(f2.x), f2bf(f2.y), f2bf(f2.z), f2bf(f2.w),
                    f2bf(f3.x), f2bf(f3.y), f2bf(f3.z), f2bf(f3.w) };
      *reinterpret_cast<bf16x8*>(&Als[ahalf * 2 + 0][arow][0]) = v0;
      *reinterpret_cast<bf16x8*>(&Als[ahalf * 2 + 1][arow][0]) = v1;
    }
    {
      size_t base = (size_t)(n0 + brow) * KDIM + kt + bq * 8;
      bf16x8 w = *reinterpret_cast<const bf16x8*>(&Bbf[base]);
      *reinterpret_cast<bf16x8*>(&Bls[bq][brow][0]) = w;
    }
    __syncthreads();
    bf16x8 af[4], bfr[2];
#pragma unroll
    for (int r = 0; r < 4; ++r)
      af[r] = *reinterpret_cast<const bf16x8*>(&Als[kb][wm * 64 + r * 16 + l15][0]);
#pragma unroll
    for (int s = 0; s < 2; ++s)
      bfr[s] = *reinterpret_cast<const bf16x8*>(&Bls[kb][wn * 32 + s * 16 + l15][0]);
#pragma unroll
    for (int r = 0; r < 4; ++r)
#pragma unroll
      for (int s = 0; s < 2; ++s)
        acc[r][s] = __builtin_amdgcn_mfma_f32_16x16x32_bf16(af[r], bfr[s], acc[r][s], 0, 0, 0);
    __syncthreads();
  }

  const int r0 = (lane >> 4) * 4;
#pragma unroll
  for (int s = 0; s < 2; ++s) {
    int col = n0 + wn * 32 + s * 16 + l15;
    float sc = g[col] * rsqrtf(var[col] + 1e-5f);
    float sh = beta[col] - mean[col] * sc;
#pragma unroll
    for (int r = 0; r < 4; ++r) {
      int rowb = m0 + wm * 64 + r * 16 + r0;
#pragma unroll
      for (int j = 0; j < 4; ++j) {
        int row = rowb + j;
        float v = acc[r][s][j] * sc + sh;
        if (FUSE) {
          v += resid[(size_t)row * N + col];
          v = fmaxf(v, 0.f);
        }
        if (OBF16) ((short*)Cv)[(size_t)row * N + col] = f2bf(v);
        else __builtin_nontemporal_store(v, &((float*)Cv)[(size_t)row * N + col]);
      }
    }
  }
}

// ---------- out0 = relu(x0 + gather(srcb_bf16,w)/(den+eps)) ----------
__global__ __launch_bounds__(256) void k_out0_v4(
    const short* __restrict__ srcb, const float* __restrict__ x0,
    const int* __restrict__ offs, const int* __restrict__ bsum,
    const int* __restrict__ lens, const int* __restrict__ intA,
    const float* __restrict__ fW, float* __restrict__ out0) {
  int row = blockIdx.x * 4 + (threadIdx.x >> 6);
  int lane = threadIdx.x & 63;
  int c4 = lane * 4;
  int key = NKEY_P + row;
  int st = g_off(offs, bsum, key);
  int ln = lens[key];
  float ax = 0.f, ay = 0.f, az = 0.f, aw = 0.f, den = 0.f;
  for (int i = 0; i < ln; ++i) {
    int sr = intA[st + i];
    float w = fW[st + i - NKEY_P];
    short4 v = *reinterpret_cast<const short4*>(&srcb[(size_t)sr * C0d + c4]);
    ax += bf2f(v.x) * w; ay += bf2f(v.y) * w;
    az += bf2f(v.z) * w; aw += bf2f(v.w) * w;
    den += w;
  }
  float inv = 1.f / (den + 1e-6f);
  size_t o = (size_t)row * C0d + c4;
  float4 xv = *reinterpret_cast<const float4*>(&x0[o]);
  f32x4 r;
  r.x = fmaxf(xv.x + ax * inv, 0.f);
  r.y = fmaxf(xv.y + ay * inv, 0.f);
  r.z = fmaxf(xv.z + az * inv, 0.f);
  r.w = fmaxf(xv.w + aw * inv, 0.f);
  __builtin_nontemporal_store(r, reinterpret_cast<f32x4*>(&out0[o]));
}

// ---------- xdf(bf16) = bn1( gd/den * skip + gb/den ) ----------
__global__ __launch_bounds__(256) void k_out1_pre_v4(
    const short* __restrict__ xm2, const float* __restrict__ x0,
    const int* __restrict__ offs, const int* __restrict__ bsum,
    const int* __restrict__ lens, const int* __restrict__ intA,
    const int* __restrict__ intB, const float* __restrict__ fW,
    const float* __restrict__ skip_w,
    const float* __restrict__ g, const float* __restrict__ beta,
    const float* __restrict__ mean, const float* __restrict__ var,
    short* __restrict__ xdf) {
  int row = blockIdx.x * 4 + (threadIdx.x >> 6);
  int lane = threadIdx.x & 63;
  int c4 = lane * 4;
  int key = NKEY_P + NKEY_0 + row;
  int st = g_off(offs, bsum, key);
  int ln = lens[key];
  float bx = 0.f, by = 0.f, bz = 0.f, bw = 0.f;
  float dx = 0.f, dy = 0.f, dz = 0.f, dw = 0.f, den = 0.f;
  for (int i = 0; i < ln; ++i) {
    int pr = intA[st + i];
    int sr = intB[st + i - (NKEY_P + NKEY_0)];
    float w = fW[st + i - NKEY_P];
    short4 vb = *reinterpret_cast<const short4*>(&xm2[(size_t)pr * C0d + c4]);
    float4 vd = *reinterpret_cast<const float4*>(&x0[(size_t)sr * C0d + c4]);
    bx += bf2f(vb.x) * w; by += bf2f(vb.y) * w;
    bz += bf2f(vb.z) * w; bw += bf2f(vb.w) * w;
    dx += vd.x * w; dy += vd.y * w; dz += vd.z * w; dw += vd.w * w;
    den += w;
  }
  float inv = 1.f / (den + 1e-6f);
  float4 sk = *reinterpret_cast<const float4*>(&skip_w[c4]);
  float4 gg = *reinterpret_cast<const float4*>(&g[c4]);
  float4 bb = *reinterpret_cast<const float4*>(&beta[c4]);
  float4 mm = *reinterpret_cast<const float4*>(&mean[c4]);
  float4 vv = *reinterpret_cast<const float4*>(&var[c4]);
  float s0 = gg.x * rsqrtf(vv.x + 1e-5f), h0 = bb.x - mm.x * s0;
  float s1 = gg.y * rsqrtf(vv.y + 1e-5f), h1 = bb.y - mm.y * s1;
  float s2 = gg.z * rsqrtf(vv.z + 1e-5f), h2 = bb.z - mm.z * s2;
  float s3 = gg.w * rsqrtf(vv.w + 1e-5f), h3 = bb.w - mm.w * s3;
  short4 o;
  o.x = f2bf((dx * inv * sk.x + bx * inv) * s0 + h0);
  o.y = f2bf((dy * inv * sk.y + by * inv) * s1 + h1);
  o.z = f2bf((dz * inv * sk.z + bz * inv) * s2 + h2);
  o.w = f2bf((dw * inv * sk.w + bw * inv) * s3 + h3);
  *reinterpret_cast<short4*>(&xdf[(size_t)row * C0d + c4]) = o;
}

extern "C" void kernel_launch(void* const* d_in, const int* in_sizes, int n_in,
                              void* d_out, int out_size, void* d_ws, size_t ws_size,
                              hipStream_t stream) {
  const float* x0   = (const float*)d_in[0];
  const float* x1   = (const float*)d_in[1];
  const int*   idx0 = (const int*)d_in[2];
  const int*   idx1 = (const int*)d_in[3];
  const float* w0   = (const float*)d_in[4];
  const float* w1   = (const float*)d_in[5];
  const float* loc  = (const float*)d_in[6];
  const float* W01  = (const float*)d_in[7];
  const float* bn01_g = (const float*)d_in[8];
  const float* bn01_b = (const float*)d_in[9];
  const float* bn01_m = (const float*)d_in[10];
  const float* bn01_v = (const float*)d_in[11];
  const float* dw_w   = (const float*)d_in[12];
  const float* skip_w = (const float*)d_in[13];
  const float* bn1_g  = (const float*)d_in[14];
  const float* bn1_b  = (const float*)d_in[15];
  const float* bn1_m  = (const float*)d_in[16];
  const float* bn1_v  = (const float*)d_in[17];
  const float* conv_w = (const float*)d_in[18];
  const float* bn2_g  = (const float*)d_in[19];
  const float* bn2_b  = (const float*)d_in[20];
  const float* bn2_m  = (const float*)d_in[21];
  const float* bn2_v  = (const float*)d_in[22];

  float* out = (float*)d_out;
  float* num0 = out;                       // out0 [131072 x 256]
  float* out1 = out + 33554432;            // out1 [32768 x 512]

  // ---- workspace layout ----
  int*   counts = (int*)d_ws;              // NKEYS (-> local-scanned offsets)
  int*   cursor = counts + NKEYS;          // NKEYS (-> lengths)
  int*   bsum   = cursor + NKEYS;          // 512 (-> block-total prefix)
  int*   intA   = bsum + 512;              // 393216
  int*   intB   = intA + 393216;           // 131072
  float* fW     = (float*)(intB + 131072); // 262144
  float* dwT    = fW + 262144;             // 2560 (2304 used)
  short* W01bf  = (short*)(dwT + 2560);    // 131072 bf16
  short* cwbf   = W01bf + 131072;          // 131072 bf16
  short* xm2    = cwbf + 131072;           // 8,388,608 bf16
  short* srcb   = xm2 + 8388608;           // 8,388,608 bf16
  short* xdf    = srcb + 8388608;          // 8,388,608 bf16

  const int nbp = Bb * NPIX;               // 131072

  // prep: zero CSR counters + cvt W01/conv_w + transpose dw
  k_prep<<<(PREP_T3 + 255) / 256, 256, 0, stream>>>(
      (int4*)d_ws, W01, W01bf, conv_w, cwbf, dw_w, dwT);

  // CSR build (scan_add folded into consumers via bsum)
  k_count<<<nbp / 256, 256, 0, stream>>>(idx0, idx1, loc, counts);
  k_scan_block<<<SCAN_BLOCKS, 256, 0, stream>>>(counts, bsum);
  k_scan_top<<<1, 512, 0, stream>>>(bsum);
  k_fill<<<nbp / 256, 256, 0, stream>>>(idx0, idx1, w0, w1, loc, counts, bsum,
                                        cursor, intA, intB, fW);

  // fused token2map + dw-conv -> xm2 (bf16)
  k_conv_v4<<<Bb * 4096 / 4, 256, 0, stream>>>(x0, counts, bsum, cursor, intA, dwT, xm2);

  // srcb(bf16) = bn01(x1 @ W01^T)   [32768 x 256]
  {
    dim3 grid(32768 / 128, 256 / 64);
    k_gemm_mfma<512, false, false, true><<<grid, 256, 0, stream>>>(
        (const void*)x1, W01bf, bn01_g, bn01_b, bn01_m, bn01_v, nullptr, (void*)srcb, 256);
  }

  // out0 = relu(x0 + gather(srcb))
  k_out0_v4<<<nbp / 4, 256, 0, stream>>>(srcb, x0, counts, bsum, cursor, intA, fW, num0);

  // xdf(bf16) = bn1(gather_d*skip + gather_b)
  k_out1_pre_v4<<<Bb * N1T / 4, 256, 0, stream>>>(xm2, x0, counts, bsum, cursor, intA,
                                                  intB, fW, skip_w,
                                                  bn1_g, bn1_b, bn1_m, bn1_v, xdf);

  // out1 = relu(x1 + bn2(xdf @ conv_w^T))  [32768 x 512]
  {
    dim3 grid(32768 / 128, 512 / 64);
    k_gemm_mfma<256, true, true, false><<<grid, 256, 0, stream>>>(
        (const void*)xdf, cwbf, bn2_g, bn2_b, bn2_m, bn2_v, x1, (void*)out1, 512);
  }
}